// Round 10
// baseline (575.874 us; speedup 1.0000x reference)
//
#include <hip/hip_runtime.h>
#include <math.h>

#define B    512
#define L    1024
#define K    8
#define NR   512
#define S    20
#define EXT  26
#define SS   (S*S)            // 400
#define PD   24               // padded matrix dim (zero pad is matmul-self-consistent)
#define PDSQ (PD*PD)          // 576
#define ROWF (K*EXT)          // 208 floats per (b,l)
#define ROWQ ((EXT*ROWF)/4)   // 1352 float4 per b in the LUT
#define BROW (L*ROWF)         // 212992 floats per b

typedef float f4 __attribute__((ext_vector_type(4)));

__device__ __forceinline__ float softplusf(float x) {
    return fmaxf(x, 0.0f) + log1pf(expf(-fabsf(x)));
}

// wave-local ordering fence: per-wave DS ops complete in order on CDNA, so
// for a wave working on its OWN LDS patch this replaces __syncthreads.
__device__ __forceinline__ void wave_fence() {
    __builtin_amdgcn_wave_barrier();
}

// ---------------------------------------------------------------------------
// Kernel 1: expm -> LUT in d_ws. VERBATIM the r2 kernel (verified passed,
// absmax 1.22e-4). Block = one b (512 blocks, 512 threads = 8 waves). Wave w
// owns matrix k=w. Writes the 26x208 row LUT for its b to global workspace
// (B * 1352 float4 = 11.1 MB; r2 confirmed ws_size is sufficient).
// ---------------------------------------------------------------------------
__global__ __launch_bounds__(512, 2) void expm_kernel(
    const int*   __restrict__ rate_indices,  // B
    const float* __restrict__ tau_kernel,    // NR
    const float* __restrict__ exch,          // K,S,S
    const float* __restrict__ freq,          // S
    float*       __restrict__ lut)           // B,26,208
{
    __shared__ __align__(16) float M[K][2][PDSQ];   // 36864 B
    __shared__ __align__(16) float Row[EXT*ROWF];   // 21632 B
    __shared__ float diag_sh[K][S];
    __shared__ float mue_sh[K];

    const int b    = blockIdx.x;
    const int t    = threadIdx.x;
    const int w    = t >> 6;          // wave id == matrix k
    const int lane = t & 63;
    const int li = lane >> 3, lj = lane & 7;
    const int r0 = 3*li, c0 = 3*lj;   // 3x3 tile origin in 24x24

    // ---- phase 0: Row LUT init (cells tiles never write) ----
    for (int e = t; e < EXT*ROWF; e += 512) {
        int row = e / ROWF, c = e - row*ROWF;
        int k = c / EXT, s = c - k*EXT;
        (void)k;
        if (row < S) {
            if (s >= S) Row[e] = 0.f;              // pad cols only; P cells skipped
        } else {
            Row[e] = (s == row) ? 1.f : 0.f;       // one-hot rows
        }
    }
    float* M0 = &M[w][0][0];
    float* M1 = &M[w][1][0];
    for (int e = lane; e < 2*PDSQ; e += 64) M0[e] = 0.f;  // zero both buffers
    float tau = softplusf(tau_kernel[rate_indices[b]]);
    wave_fence();

    // ---- phase 1: build A = (Q_w / mue) * tau / 2^6 in M0 ----
    const float* E = exch + w * SS;
    for (int e = lane; e < SS; e += 64) {
        int r = e / S, c = e - r*S;
        float v = 0.f;
        if (r != c)
            v = softplusf(0.5f * (E[r*S + c] + E[c*S + r])) * freq[c];
        M0[r*PD + c] = v;
    }
    wave_fence();
    if (lane < S) {
        float d = 0.f;
        #pragma unroll
        for (int j = 0; j < S; ++j) d += M0[lane*PD + j];
        diag_sh[w][lane] = d;
    }
    wave_fence();
    if (lane == 0) {
        float m = 0.f;
        #pragma unroll
        for (int s = 0; s < S; ++s) m += freq[s] * diag_sh[w][s];
        mue_sh[w] = fmaxf(m, 1e-16f);
    }
    wave_fence();
    {
        float scale = tau * 0.015625f;
        float mue   = mue_sh[w];
        for (int e = lane; e < SS; e += 64) {
            int r = e / S, c = e - r*S;
            float v = (r == c) ? -diag_sh[w][r] : M0[r*PD + c];
            M0[r*PD + c] = (v / mue) * scale;
        }
    }
    wave_fence();

    // ---- expm: A cols in regs, P=I+A, order-10 Taylor, 6 squarings ----
    float Ac[S][3];
    #pragma unroll
    for (int j = 0; j < S; ++j) {
        #pragma unroll
        for (int d = 0; d < 3; ++d)
            Ac[j][d] = M0[j*PD + c0 + d];
    }

    float P[3][3];
    #pragma unroll
    for (int dr = 0; dr < 3; ++dr)
        #pragma unroll
        for (int dc = 0; dc < 3; ++dc) {
            int r = r0 + dr, c = c0 + dc;
            P[dr][dc] = M0[r*PD + c] + ((r == c && r < S) ? 1.f : 0.f);
        }

    const float* Tc = M0;
    float* Tn = M1;
    #pragma unroll 1
    for (int i = 2; i <= 10; ++i) {
        float C[3][3] = {{0.f,0.f,0.f},{0.f,0.f,0.f},{0.f,0.f,0.f}};
        #pragma unroll
        for (int jc = 0; jc < 5; ++jc) {
            float4 a0 = *(const float4*)&Tc[(r0+0)*PD + 4*jc];
            float4 a1 = *(const float4*)&Tc[(r0+1)*PD + 4*jc];
            float4 a2 = *(const float4*)&Tc[(r0+2)*PD + 4*jc];
            float t0[4] = {a0.x, a0.y, a0.z, a0.w};
            float t1[4] = {a1.x, a1.y, a1.z, a1.w};
            float t2[4] = {a2.x, a2.y, a2.z, a2.w};
            #pragma unroll
            for (int dj = 0; dj < 4; ++dj) {
                int j = 4*jc + dj;
                #pragma unroll
                for (int dc = 0; dc < 3; ++dc) {
                    C[0][dc] = fmaf(t0[dj], Ac[j][dc], C[0][dc]);
                    C[1][dc] = fmaf(t1[dj], Ac[j][dc], C[1][dc]);
                    C[2][dc] = fmaf(t2[dj], Ac[j][dc], C[2][dc]);
                }
            }
        }
        float inv = 1.0f / (float)i;
        #pragma unroll
        for (int dr = 0; dr < 3; ++dr)
            #pragma unroll
            for (int dc = 0; dc < 3; ++dc) {
                C[dr][dc] *= inv;
                P[dr][dc] += C[dr][dc];
                Tn[(r0+dr)*PD + c0 + dc] = C[dr][dc];
            }
        wave_fence();
        float* tmp = (float*)Tc; Tc = Tn; Tn = tmp;
    }

    #pragma unroll 1
    for (int sq = 0; sq < 6; ++sq) {
        #pragma unroll
        for (int dr = 0; dr < 3; ++dr)
            #pragma unroll
            for (int dc = 0; dc < 3; ++dc)
                Tn[(r0+dr)*PD + c0 + dc] = P[dr][dc];
        wave_fence();
        const float* Pb = Tn;
        float C[3][3] = {{0.f,0.f,0.f},{0.f,0.f,0.f},{0.f,0.f,0.f}};
        #pragma unroll
        for (int jc = 0; jc < 5; ++jc) {
            float4 a0 = *(const float4*)&Pb[(r0+0)*PD + 4*jc];
            float4 a1 = *(const float4*)&Pb[(r0+1)*PD + 4*jc];
            float4 a2 = *(const float4*)&Pb[(r0+2)*PD + 4*jc];
            float t0[4] = {a0.x, a0.y, a0.z, a0.w};
            float t1[4] = {a1.x, a1.y, a1.z, a1.w};
            float t2[4] = {a2.x, a2.y, a2.z, a2.w};
            float cb[4][3];
            #pragma unroll
            for (int dj = 0; dj < 4; ++dj)
                #pragma unroll
                for (int dc = 0; dc < 3; ++dc)
                    cb[dj][dc] = Pb[(4*jc + dj)*PD + c0 + dc];
            #pragma unroll
            for (int dj = 0; dj < 4; ++dj)
                #pragma unroll
                for (int dc = 0; dc < 3; ++dc) {
                    C[0][dc] = fmaf(t0[dj], cb[dj][dc], C[0][dc]);
                    C[1][dc] = fmaf(t1[dj], cb[dj][dc], C[1][dc]);
                    C[2][dc] = fmaf(t2[dj], cb[dj][dc], C[2][dc]);
                }
        }
        #pragma unroll
        for (int dr = 0; dr < 3; ++dr)
            #pragma unroll
            for (int dc = 0; dc < 3; ++dc)
                P[dr][dc] = C[dr][dc];
        float* tmp = (float*)Tc; Tc = Tn; Tn = tmp;
        wave_fence();
    }

    // ---- P tiles -> Row LUT ----
    #pragma unroll
    for (int dr = 0; dr < 3; ++dr) {
        int r = r0 + dr; if (r >= S) continue;
        #pragma unroll
        for (int dc = 0; dc < 3; ++dc) {
            int c = c0 + dc; if (c >= S) continue;
            Row[r*ROWF + w*EXT + c] = P[dr][dc];
        }
    }
    __syncthreads();

    // ---- LUT writeback: 21.6 KB coalesced float4 copy to d_ws ----
    f4* dst = (f4*)lut + (size_t)b * ROWQ;
    const f4* src = (const f4*)Row;
    for (int e = t; e < ROWQ; e += 512) dst[e] = src[e];
}

// ---------------------------------------------------------------------------
// Kernel 2: lockstep linear stream (the fill's access pattern).
// 53248 threads total (208 blocks x 256). Thread t owns FIXED coordinates
// q = t % 52 (f4-column) and l = t / 52, and sweeps b = 0..511.
//   read : inp = inputs[b*L + l]            (4 KB slice, L2-broadcast-hot)
//   gather: lut4[b*1352 + inp*52 + q]       (21.6 KB slice/iter, L2-hot;
//           per wave ~2 distinct inp rows -> ~2 coalesced bursts)
//   store: out4[b*53248 + t]                (PERFECTLY linear; whole GPU
//           writes batch b's contiguous 852 KB window per iteration)
// Instantaneous HBM write footprint ~1 MB (vs ~50 MB in all prior variants)
// -> DRAM row-buffer locality like fillBufferAligned's 6.2 TB/s pattern.
// ---------------------------------------------------------------------------
__global__ __launch_bounds__(256, 4) void stream2_kernel(
    const int*   __restrict__ inputs,   // B,L
    const float* __restrict__ lut,      // B,26,208
    float*       __restrict__ out)      // B,L,208
{
    const int t = blockIdx.x * 256 + threadIdx.x;   // 0..53247
    const int l = t / 52;
    const int q = t - l * 52;

    const f4* lut4 = (const f4*)lut;
    f4* out4 = (f4*)out;
    const int* inp_base = inputs + l;

    #pragma unroll 4
    for (int b = 0; b < B; ++b) {
        int inp = inp_base[b * L];
        f4 v = lut4[b * ROWQ + inp * 52 + q];
        out4[(size_t)b * (BROW/4) + t] = v;
    }
}

// ---------------------------------------------------------------------------
extern "C" void kernel_launch(void* const* d_in, const int* in_sizes, int n_in,
                              void* d_out, int out_size, void* d_ws, size_t ws_size,
                              hipStream_t stream) {
    const int*   inputs  = (const int*)  d_in[0];  // (B,L) int32
    const int*   rate_ix = (const int*)  d_in[1];  // (B,) int32
    const float* tau_k   = (const float*)d_in[2];  // (NR,) f32
    const float* exch    = (const float*)d_in[3];  // (K,S,S) f32
    const float* freq    = (const float*)d_in[4];  // (S,) f32
    float* out = (float*)d_out;
    float* lut = (float*)d_ws;                     // needs 11,075,584 B (r2-verified)

    (void)in_sizes; (void)n_in; (void)out_size; (void)ws_size;

    expm_kernel<<<B, 512, 0, stream>>>(rate_ix, tau_k, exch, freq, lut);
    stream2_kernel<<<208, 256, 0, stream>>>(inputs, lut, out);
}

// Round 14
// 512.043 us; speedup vs baseline: 1.1247x; 1.1247x over previous
//
#include <hip/hip_runtime.h>
#include <math.h>

#define B    512
#define L    1024
#define K    8
#define NR   512
#define S    20
#define EXT  26
#define SS   (S*S)            // 400
#define PD   24               // padded matrix dim (zero pad is matmul-self-consistent)
#define PDSQ (PD*PD)          // 576
#define ROWF (K*EXT)          // 208 floats per (b,l)
#define BROW (L*ROWF)         // 212992 floats per b

typedef float f4 __attribute__((ext_vector_type(4)));

__device__ __forceinline__ float softplusf(float x) {
    return fmaxf(x, 0.0f) + log1pf(expf(-fabsf(x)));
}

// wave-local ordering fence: per-wave DS ops complete in order on CDNA, so
// for a wave working on its OWN LDS patch this replaces __syncthreads.
__device__ __forceinline__ void wave_fence() {
    __builtin_amdgcn_wave_barrier();
}

// ---------------------------------------------------------------------------
// Fused kernel, bucket-store variant. Block = one b (512 blocks, 512 thr =
// 8 waves, 2 blocks/CU). Phases 0/1/expm identical to the verified 478us
// kernel. NEW phase 2: counting-sort l by symbol (26 buckets, LDS scratch
// aliased over the dead M buffer), then wave w streams symbols {w, w+8, ...}:
// row loaded ONCE into regs (lane<52 holds f4 #lane), stores are
// loop-invariant-data, dependence-free, back-to-back 832B bursts — the
// fill's register-source store pattern. Tests (and exploits) the theory
// that gather-dependent store data is what held all variants at 2.7 TB/s.
// ---------------------------------------------------------------------------
__global__ __launch_bounds__(512, 2) void fused_kernel(
    const int*   __restrict__ inputs,        // B,L
    const int*   __restrict__ rate_indices,  // B
    const float* __restrict__ tau_kernel,    // NR
    const float* __restrict__ exch,          // K,S,S
    const float* __restrict__ freq,          // S
    float* __restrict__ out)                 // B,L,208
{
    __shared__ __align__(16) float M[K][2][PDSQ];   // 36864 B (reused as bucket scratch)
    __shared__ __align__(16) float Row[EXT*ROWF];   // 21632 B
    __shared__ int   inp_sh[L];                     // 4096 B
    __shared__ float diag_sh[K][S];
    __shared__ float mue_sh[K];

    const int b    = blockIdx.x;
    const int t    = threadIdx.x;
    const int w    = t >> 6;          // wave id == matrix k
    const int lane = t & 63;
    const int li = lane >> 3, lj = lane & 7;
    const int r0 = 3*li, c0 = 3*lj;   // 3x3 tile origin in 24x24

    // ---- phase 0 (no cross-wave ordering needed until the first barrier) ----
    for (int u = t; u < L; u += 512) inp_sh[u] = inputs[b*L + u];
    for (int e = t; e < EXT*ROWF; e += 512) {
        int row = e / ROWF, c = e - row*ROWF;
        int k = c / EXT, s = c - k*EXT;
        (void)k;
        if (row < S) {
            if (s >= S) Row[e] = 0.f;              // pad cols only; P cells skipped
        } else {
            Row[e] = (s == row) ? 1.f : 0.f;       // one-hot rows
        }
    }
    float* M0 = &M[w][0][0];
    float* M1 = &M[w][1][0];
    for (int e = lane; e < 2*PDSQ; e += 64) M0[e] = 0.f;  // zero both buffers
    // tau: uniform loads, computed redundantly in every lane
    float tau = softplusf(tau_kernel[rate_indices[b]]);
    wave_fence();

    // ---- phase 1: build A = (Q_w / mue) * tau / 2^6 in M0 ----
    const float* E = exch + w * SS;
    for (int e = lane; e < SS; e += 64) {
        int r = e / S, c = e - r*S;
        float v = 0.f;
        if (r != c)
            v = softplusf(0.5f * (E[r*S + c] + E[c*S + r])) * freq[c];
        M0[r*PD + c] = v;
    }
    wave_fence();
    if (lane < S) {
        float d = 0.f;
        #pragma unroll
        for (int j = 0; j < S; ++j) d += M0[lane*PD + j];
        diag_sh[w][lane] = d;
    }
    wave_fence();
    if (lane == 0) {
        float m = 0.f;
        #pragma unroll
        for (int s = 0; s < S; ++s) m += freq[s] * diag_sh[w][s];
        mue_sh[w] = fmaxf(m, 1e-16f);
    }
    wave_fence();
    {
        float scale = tau * 0.015625f;
        float mue   = mue_sh[w];
        for (int e = lane; e < SS; e += 64) {
            int r = e / S, c = e - r*S;
            float v = (r == c) ? -diag_sh[w][r] : M0[r*PD + c];
            M0[r*PD + c] = (v / mue) * scale;
        }
    }
    wave_fence();

    // ---- expm: A cols in regs, P=I+A, order-10 Taylor, 6 squarings ----
    float Ac[S][3];
    #pragma unroll
    for (int j = 0; j < S; ++j) {
        #pragma unroll
        for (int d = 0; d < 3; ++d)
            Ac[j][d] = M0[j*PD + c0 + d];
    }

    float P[3][3];
    #pragma unroll
    for (int dr = 0; dr < 3; ++dr)
        #pragma unroll
        for (int dc = 0; dc < 3; ++dc) {
            int r = r0 + dr, c = c0 + dc;
            P[dr][dc] = M0[r*PD + c] + ((r == c && r < S) ? 1.f : 0.f);
        }

    const float* Tc = M0;
    float* Tn = M1;
    #pragma unroll 1
    for (int i = 2; i <= 10; ++i) {
        float C[3][3] = {{0.f,0.f,0.f},{0.f,0.f,0.f},{0.f,0.f,0.f}};
        #pragma unroll
        for (int jc = 0; jc < 5; ++jc) {
            float4 a0 = *(const float4*)&Tc[(r0+0)*PD + 4*jc];
            float4 a1 = *(const float4*)&Tc[(r0+1)*PD + 4*jc];
            float4 a2 = *(const float4*)&Tc[(r0+2)*PD + 4*jc];
            float t0[4] = {a0.x, a0.y, a0.z, a0.w};
            float t1[4] = {a1.x, a1.y, a1.z, a1.w};
            float t2[4] = {a2.x, a2.y, a2.z, a2.w};
            #pragma unroll
            for (int dj = 0; dj < 4; ++dj) {
                int j = 4*jc + dj;
                #pragma unroll
                for (int dc = 0; dc < 3; ++dc) {
                    C[0][dc] = fmaf(t0[dj], Ac[j][dc], C[0][dc]);
                    C[1][dc] = fmaf(t1[dj], Ac[j][dc], C[1][dc]);
                    C[2][dc] = fmaf(t2[dj], Ac[j][dc], C[2][dc]);
                }
            }
        }
        float inv = 1.0f / (float)i;
        #pragma unroll
        for (int dr = 0; dr < 3; ++dr)
            #pragma unroll
            for (int dc = 0; dc < 3; ++dc) {
                C[dr][dc] *= inv;
                P[dr][dc] += C[dr][dc];
                Tn[(r0+dr)*PD + c0 + dc] = C[dr][dc];
            }
        wave_fence();
        float* tmp = (float*)Tc; Tc = Tn; Tn = tmp;
    }

    #pragma unroll 1
    for (int sq = 0; sq < 6; ++sq) {
        #pragma unroll
        for (int dr = 0; dr < 3; ++dr)
            #pragma unroll
            for (int dc = 0; dc < 3; ++dc)
                Tn[(r0+dr)*PD + c0 + dc] = P[dr][dc];
        wave_fence();
        const float* Pb = Tn;
        float C[3][3] = {{0.f,0.f,0.f},{0.f,0.f,0.f},{0.f,0.f,0.f}};
        #pragma unroll
        for (int jc = 0; jc < 5; ++jc) {
            float4 a0 = *(const float4*)&Pb[(r0+0)*PD + 4*jc];
            float4 a1 = *(const float4*)&Pb[(r0+1)*PD + 4*jc];
            float4 a2 = *(const float4*)&Pb[(r0+2)*PD + 4*jc];
            float t0[4] = {a0.x, a0.y, a0.z, a0.w};
            float t1[4] = {a1.x, a1.y, a1.z, a1.w};
            float t2[4] = {a2.x, a2.y, a2.z, a2.w};
            float cb[4][3];
            #pragma unroll
            for (int dj = 0; dj < 4; ++dj)
                #pragma unroll
                for (int dc = 0; dc < 3; ++dc)
                    cb[dj][dc] = Pb[(4*jc + dj)*PD + c0 + dc];
            #pragma unroll
            for (int dj = 0; dj < 4; ++dj)
                #pragma unroll
                for (int dc = 0; dc < 3; ++dc) {
                    C[0][dc] = fmaf(t0[dj], cb[dj][dc], C[0][dc]);
                    C[1][dc] = fmaf(t1[dj], cb[dj][dc], C[1][dc]);
                    C[2][dc] = fmaf(t2[dj], cb[dj][dc], C[2][dc]);
                }
        }
        #pragma unroll
        for (int dr = 0; dr < 3; ++dr)
            #pragma unroll
            for (int dc = 0; dc < 3; ++dc)
                P[dr][dc] = C[dr][dc];
        float* tmp = (float*)Tc; Tc = Tn; Tn = tmp;
        wave_fence();
    }

    // ---- P tiles -> Row LUT (only r<20, c<20 cells; disjoint from init) ----
    #pragma unroll
    for (int dr = 0; dr < 3; ++dr) {
        int r = r0 + dr; if (r >= S) continue;
        #pragma unroll
        for (int dc = 0; dc < 3; ++dc) {
            int c = c0 + dc; if (c >= S) continue;
            Row[r*ROWF + w*EXT + c] = P[dr][dc];
        }
    }
    __syncthreads();   // Row complete; M is DEAD from here -> reuse as scratch

    // ---- phase 2a: counting-sort l by symbol (26 buckets) in M scratch ----
    // scratch layout (ints over M): [0..25] counts/cursors, [32..58] base,
    // [64..1087] lists.
    int* scratch = (int*)&M[0][0][0];
    int* counts  = scratch;        // 26
    int* base    = scratch + 32;   // 27
    int* lists   = scratch + 64;   // 1024
    if (t < 26) counts[t] = 0;
    __syncthreads();
    for (int l = t; l < L; l += 512)
        atomicAdd(&counts[inp_sh[l]], 1);
    __syncthreads();
    if (t == 0) {
        int run = 0;
        #pragma unroll
        for (int s = 0; s < EXT; ++s) {
            int c = counts[s];
            base[s]   = run;
            counts[s] = run;       // becomes the scatter cursor
            run += c;
        }
        base[EXT] = run;           // == 1024
    }
    __syncthreads();
    for (int l = t; l < L; l += 512) {
        int s   = inp_sh[l];
        int pos = atomicAdd(&counts[s], 1);
        lists[pos] = l;
    }
    __syncthreads();

    // ---- phase 2b: register-source streaming. Wave w owns symbols
    // {w, w+8, w+16, w+24}. Row held in regs (lane<52: one f4 each);
    // stores are dependence-free 832B bursts, data loop-invariant. ----
    const f4* Row4 = (const f4*)Row;
    f4* outb = (f4*)out + (size_t)b * (BROW/4);
    if (lane < 52) {
        #pragma unroll 1
        for (int s = w; s < EXT; s += 8) {
            f4 v = Row4[s * 52 + lane];
            int lo = base[s], hi = base[s + 1];
            #pragma unroll 4
            for (int ii = lo; ii < hi; ++ii) {
                int l = lists[ii];          // uniform LDS read (broadcast)
                outb[l * 52 + lane] = v;    // 832B contiguous, reg-source
            }
        }
    }
}

// ---------------------------------------------------------------------------
extern "C" void kernel_launch(void* const* d_in, const int* in_sizes, int n_in,
                              void* d_out, int out_size, void* d_ws, size_t ws_size,
                              hipStream_t stream) {
    const int*   inputs  = (const int*)  d_in[0];  // (B,L) int32
    const int*   rate_ix = (const int*)  d_in[1];  // (B,) int32
    const float* tau_k   = (const float*)d_in[2];  // (NR,) f32
    const float* exch    = (const float*)d_in[3];  // (K,S,S) f32
    const float* freq    = (const float*)d_in[4];  // (S,) f32
    float* out = (float*)d_out;

    (void)d_ws; (void)ws_size; (void)in_sizes; (void)n_in; (void)out_size;

    fused_kernel<<<B, 512, 0, stream>>>(inputs, rate_ix, tau_k, exch, freq, out);
}